// Round 3
// baseline (1124.933 us; speedup 1.0000x reference)
//
#include <hip/hip_runtime.h>

// Problem: 8192x8192 fp32 -> per-8x8-block DCT-II (orthonormal), per-block
// inf-norm `biggest`, int8 quantization indices = rint(coeff * 127/biggest).
// Output (flat fp32): [1024*1024*64 indices][1024*1024 biggest].
//
// One thread per 8x8 block. Memory-bound.
//
// R2 note: R0/R1 compiled to 44 VGPRs -> the float B[8][8] alloca was never
// promoted; threads spilled the block to scratch (launch_bounds cap didn't
// help because it's a cap, not a floor). Fix: no arrays at all — 8 named
// ext_vector(8) rows, pure SSA. Stage-2 column mix is computed TWICE
// (absmax pass, then quantize pass) so peak live set is ~72 floats instead
// of 128; the extra 512 FMA/thread is cheap (VALUBusy was 17%).
// Outputs use non-temporal stores so the 272 MB output stream doesn't evict
// the input image from the 256 MiB L3 (FETCH was already only ~134 MB).

#define IMG_H 8192
#define IMG_W 8192
#define NB1 (IMG_H / 8)
#define NB2 (IMG_W / 8)

typedef float v8f __attribute__((ext_vector_type(8)));
typedef float v4f __attribute__((ext_vector_type(4)));

// Orthonormal DCT-II matrix M[element][freq] for n=8, fp32-exact constants.
// M[e][f] = 0.5*cos(pi*(2e+1)*f/16); M[e][0] = sqrt(1/8) == 0.5*cos(pi/4).
constexpr float kc1 = 0.4903926402016152f;
constexpr float kc2 = 0.4619397662556434f;
constexpr float kc3 = 0.4157348061512726f;
constexpr float kc4 = 0.35355339059327373f;
constexpr float kc5 = 0.2777851165098011f;
constexpr float kc6 = 0.1913417161825449f;
constexpr float kc7 = 0.0975451610080642f;
constexpr float M_[8][8] = {
    { kc4,  kc1,  kc2,  kc3,  kc4,  kc5,  kc6,  kc7},
    { kc4,  kc3,  kc6, -kc7, -kc4, -kc1, -kc2, -kc5},
    { kc4,  kc5, -kc6, -kc1, -kc4,  kc7,  kc2,  kc3},
    { kc4,  kc7, -kc2, -kc5,  kc4,  kc3, -kc6, -kc1},
    { kc4, -kc7, -kc2,  kc5,  kc4, -kc3, -kc6,  kc1},
    { kc4, -kc5, -kc6,  kc1, -kc4, -kc7,  kc2, -kc3},
    { kc4, -kc3,  kc6,  kc7, -kc4,  kc1, -kc2,  kc5},
    { kc4, -kc1,  kc2, -kc3,  kc4, -kc5,  kc6, -kc7},
};

// Row DCT: t[h] = sum_f r[f] * M_[f][h]. Pure SSA (vector extract/insert).
__device__ __forceinline__ v8f dct_row(v8f r) {
    v8f t;
#pragma unroll
    for (int h = 0; h < 8; ++h) {
        float s = r[0] * M_[0][h];
#pragma unroll
        for (int f = 1; f < 8; ++f) s = fmaf(r[f], M_[f][h], s);
        t[h] = s;
    }
    return t;
}

__global__ __launch_bounds__(256, 4) void dct_quant_kernel(
    const float* __restrict__ x,
    float* __restrict__ out_idx,   // NB1*NB2*64 floats (int8 values as fp32)
    float* __restrict__ out_big)   // NB1*NB2 floats
{
    const int tid = blockIdx.x * blockDim.x + threadIdx.x;
    const int b1 = tid >> 10;      // tid / NB2  (NB2 == 1024)
    const int b2 = tid & 1023;     // tid % NB2

    const float* src = x + (size_t)b1 * 8 * IMG_W + (size_t)b2 * 8;

    // Load 8 rows as named SSA vectors (2 x 16B each, issued up front).
    v8f B0, B1, B2, B3, B4, B5, B6, B7;
#define LOADROW(i)                                                          \
    {                                                                       \
        const v4f* p = (const v4f*)(src + (size_t)(i) * IMG_W);             \
        v4f lo = p[0];                                                      \
        v4f hi = p[1];                                                      \
        B##i = __builtin_shufflevector(lo, hi, 0, 1, 2, 3, 4, 5, 6, 7);     \
    }
    LOADROW(0) LOADROW(1) LOADROW(2) LOADROW(3)
    LOADROW(4) LOADROW(5) LOADROW(6) LOADROW(7)
#undef LOADROW

    // Stage 1: row transform, in place. B now holds T1 = B * M.
    B0 = dct_row(B0); B1 = dct_row(B1); B2 = dct_row(B2); B3 = dct_row(B3);
    B4 = dct_row(B4); B5 = dct_row(B5); B6 = dct_row(B6); B7 = dct_row(B7);

    // Stage 2: C row g = sum_e M_[e][g] * T1 row e  (vector FMA chain).
#define COLMIX(g)                                                           \
    (M_[0][g] * B0 + M_[1][g] * B1 + M_[2][g] * B2 + M_[3][g] * B3 +        \
     M_[4][g] * B4 + M_[5][g] * B5 + M_[6][g] * B6 + M_[7][g] * B7)

    // Pass 2a: absmax only (rows discarded -> small live set).
    float big = 0.0f;
#pragma unroll
    for (int g = 0; g < 8; ++g) {
        v8f rw = COLMIX(g);
#pragma unroll
        for (int h = 0; h < 8; ++h) big = fmaxf(big, fabsf(rw[h]));
    }

    const float scale = 127.0f / big;

    // Pass 2b: recompute each row, quantize (round-half-even), nt-store.
    float* o = out_idx + (size_t)tid * 64;
#pragma unroll
    for (int g = 0; g < 8; ++g) {
        v8f rw = COLMIX(g);
        v4f q0, q1;
        q0.x = rintf(rw[0] * scale);
        q0.y = rintf(rw[1] * scale);
        q0.z = rintf(rw[2] * scale);
        q0.w = rintf(rw[3] * scale);
        q1.x = rintf(rw[4] * scale);
        q1.y = rintf(rw[5] * scale);
        q1.z = rintf(rw[6] * scale);
        q1.w = rintf(rw[7] * scale);
        __builtin_nontemporal_store(q0, (v4f*)(o + g * 8));
        __builtin_nontemporal_store(q1, (v4f*)(o + g * 8 + 4));
    }
#undef COLMIX
    __builtin_nontemporal_store(big, out_big + tid);
}

extern "C" void kernel_launch(void* const* d_in, const int* in_sizes, int n_in,
                              void* d_out, int out_size, void* d_ws, size_t ws_size,
                              hipStream_t stream) {
    const float* x = (const float*)d_in[0];
    // d_in[1] is the dct matrix; fixed function of BLOCK=8, hardcoded
    // (fp32-identical) in the kernel.
    float* out = (float*)d_out;
    float* out_idx = out;                                // (NB1,NB2,64)
    float* out_big = out + (size_t)NB1 * NB2 * 64;       // (NB1,NB2)

    const int nthreads = NB1 * NB2;   // one thread per 8x8 block
    dct_quant_kernel<<<nthreads / 256, 256, 0, stream>>>(x, out_idx, out_big);
}